// Round 2
// baseline (312.309 us; speedup 1.0000x reference)
//
#include <hip/hip_runtime.h>
#include <hip/hip_bf16.h>

#define DEVI static __device__ __forceinline__

typedef __attribute__((ext_vector_type(8))) _Float16 f16x8;
typedef __attribute__((ext_vector_type(4))) float f32x4;
typedef __attribute__((ext_vector_type(8))) unsigned short u16x8;
typedef unsigned short u16;

constexpr int NE = 1024;   // n_embd
constexpr int NH = 16;     // heads
constexpr int HD = 64;     // head dim
constexpr int SB = 4;      // batch
constexpr int SS = 2048;   // seq
constexpr int MR = SB * SS; // 8192 rows

DEVI u16 f2h(float f) {
  union { _Float16 h; u16 u; } x;
  x.h = (_Float16)f;
  return x.u;
}

DEVI void gload_lds16(const void* g, void* l) {
  __builtin_amdgcn_global_load_lds(
      (const __attribute__((address_space(1))) unsigned int*)g,
      (__attribute__((address_space(3))) unsigned int*)l, 16, 0, 0);
}

// ---------------- x fp32 -> fp16 ----------------
__global__ void k_cvt_x(const float* __restrict__ x, u16* __restrict__ xb) {
  size_t i = (size_t)blockIdx.x * 256 + threadIdx.x;   // 1,048,576 threads, 8 elems each
  const f32x4* s4 = (const f32x4*)x;
  f32x4 a = s4[2 * i], c = s4[2 * i + 1];
  u16x8 o;
  o[0] = f2h(a[0]); o[1] = f2h(a[1]); o[2] = f2h(a[2]); o[3] = f2h(a[3]);
  o[4] = f2h(c[0]); o[5] = f2h(c[1]); o[6] = f2h(c[2]); o[7] = f2h(c[3]);
  ((u16x8*)xb)[i] = o;
}

// ---------------- W [K][N] fp32 -> W^T [N][K] fp16 (4 weights) ----------------
__global__ void k_wt(const float* __restrict__ W0, const float* __restrict__ W1,
                     const float* __restrict__ W2, const float* __restrict__ W3,
                     u16* __restrict__ WT) {
  __shared__ float tile[64][65];
  const float* W = (blockIdx.z == 0) ? W0 : (blockIdx.z == 1) ? W1 : (blockIdx.z == 2) ? W2 : W3;
  u16* T = WT + (size_t)blockIdx.z * NE * NE;
  int tid = threadIdx.x, c = tid & 63, rr = tid >> 6;
  int ti = blockIdx.y * 64, tj = blockIdx.x * 64;
#pragma unroll
  for (int p = 0; p < 16; p++) {
    int r = p * 4 + rr;
    tile[r][c] = W[(size_t)(ti + r) * NE + tj + c];
  }
  __syncthreads();
#pragma unroll
  for (int p = 0; p < 16; p++) {
    int r = p * 4 + rr;
    T[(size_t)(tj + r) * NE + ti + c] = f2h(tile[c][r]);
  }
}

// ---------------- GEMM: C[M][1024] = A[M][1024] @ (BT[1024][1024])^T + bias ----------------
// MODE 0: fp16 row-major out; MODE 1: fp16 out scattered as V^T [B][H][D][S]; MODE 2: fp32 row-major out
template <int MODE>
__global__ __launch_bounds__(256) void k_gemm(const u16* __restrict__ A,
                                              const u16* __restrict__ BT,
                                              const float* __restrict__ bias,
                                              void* __restrict__ outp) {
  __shared__ __align__(16) u16 lA[128 * 64];
  __shared__ __align__(16) u16 lB[128 * 64];
  const int tid = threadIdx.x;
  const int wave = tid >> 6, lane = tid & 63;
  const int wr = wave >> 1, wc = wave & 1;
  const int fr = lane & 15, fg = lane >> 4;
  const int srow = lane >> 3;
  const int scol = ((lane & 7) ^ srow) * 8;   // pre-swizzled global source chunk
  const int mb = blockIdx.x, nb = blockIdx.y;
  f32x4 acc[4][4] = {};
  for (int kt = 0; kt < NE / 64; ++kt) {
#pragma unroll
    for (int p = 0; p < 4; p++) {
      int rb = wave * 32 + p * 8;
      gload_lds16(A + (size_t)(mb * 128 + rb + srow) * NE + kt * 64 + scol, lA + rb * 64);
      gload_lds16(BT + (size_t)(nb * 128 + rb + srow) * NE + kt * 64 + scol, lB + rb * 64);
    }
    __syncthreads();
#pragma unroll
    for (int kd = 0; kd < 2; ++kd) {
      f16x8 af[4], bg[4];
#pragma unroll
      for (int mi = 0; mi < 4; mi++) {
        int row = wr * 64 + mi * 16 + fr;
        af[mi] = *(const f16x8*)((const char*)lA + row * 128 + ((kd * 64 + fg * 16) ^ ((row & 7) << 4)));
      }
#pragma unroll
      for (int nj = 0; nj < 4; nj++) {
        int row = wc * 64 + nj * 16 + fr;
        bg[nj] = *(const f16x8*)((const char*)lB + row * 128 + ((kd * 64 + fg * 16) ^ ((row & 7) << 4)));
      }
#pragma unroll
      for (int mi = 0; mi < 4; mi++)
#pragma unroll
        for (int nj = 0; nj < 4; nj++)
          acc[mi][nj] = __builtin_amdgcn_mfma_f32_16x16x32_f16(af[mi], bg[nj], acc[mi][nj], 0, 0, 0);
    }
    __syncthreads();
  }
  float bv[4];
#pragma unroll
  for (int nj = 0; nj < 4; nj++) bv[nj] = bias[nb * 128 + wc * 64 + nj * 16 + fr];
#pragma unroll
  for (int mi = 0; mi < 4; mi++)
#pragma unroll
    for (int nj = 0; nj < 4; nj++)
#pragma unroll
      for (int r = 0; r < 4; r++) {
        int row = mb * 128 + wr * 64 + mi * 16 + fg * 4 + r;
        int col = nb * 128 + wc * 64 + nj * 16 + fr;
        float v = acc[mi][nj][r] + bv[nj];
        if constexpr (MODE == 2) {
          ((float*)outp)[(size_t)row * NE + col] = v;
        } else if constexpr (MODE == 0) {
          ((u16*)outp)[(size_t)row * NE + col] = f2h(v);
        } else {
          int b = row >> 11, s = row & (SS - 1);
          int h = col >> 6, d = col & 63;
          ((u16*)outp)[(((size_t)(b * NH + h) * HD + d) << 11) | (size_t)s] = f2h(v);
        }
      }
}

// ---------------- flash attention ----------------
// grid (S/64, H, B), 256 threads. Q,K: [B][S][H*D] fp16. VT: [B][H][D][S] fp16. AO: [B][S][H*D] fp16.
__global__ __launch_bounds__(256) void k_attn(const u16* __restrict__ Q, const u16* __restrict__ K,
                                              const u16* __restrict__ VT, u16* __restrict__ AO) {
  __shared__ __align__(16) u16 lK[64 * 64];
  __shared__ __align__(16) u16 lV[64 * 64];          // V^T tile: [d][sk]
  __shared__ __align__(16) u16 lP[4][16 * 72];       // per-wave P buffer, padded rows (72 elems)
  const int tid = threadIdx.x, wave = tid >> 6, lane = tid & 63;
  const int fr = lane & 15, fg = lane >> 4;
  const int srow = lane >> 3;
  const int scol = ((lane & 7) ^ srow) * 8;
  const int qb = blockIdx.x * 64, h = blockIdx.y, b = blockIdx.z;
  const int qrow = qb + wave * 16 + fr;
  const u16* Qp = Q + (size_t)(b * SS + qrow) * NE + h * HD;
  f16x8 qf[2] = { *(const f16x8*)(Qp + fg * 8), *(const f16x8*)(Qp + 32 + fg * 8) };
  const u16* Kg = K + (size_t)(b * SS) * NE + h * HD;
  const u16* Vg = VT + (size_t)(b * NH + h) * HD * SS;
  f32x4 acc[4] = {};
  float m_r[4], l_r[4];
#pragma unroll
  for (int r = 0; r < 4; r++) { m_r[r] = -1e30f; l_r[r] = 0.f; }
  const float SC = 8.0f * 1.44269504088896340736f;   // sqrt(64) * log2(e)
  u16* Pw = &lP[wave][0];
  for (int kt = 0; kt < SS / 64; ++kt) {
#pragma unroll
    for (int p = 0; p < 2; p++) {
      int rb = wave * 16 + p * 8;
      gload_lds16(Kg + (size_t)(kt * 64 + rb + srow) * NE + scol, lK + rb * 64);
      gload_lds16(Vg + (size_t)(rb + srow) * SS + kt * 64 + scol, lV + rb * 64);
    }
    __syncthreads();
    // S = Q K^T  (A = Q frag, B^T = K rows)
    f32x4 s[4];
#pragma unroll
    for (int c = 0; c < 4; c++) {
      f32x4 z = {};
#pragma unroll
      for (int kd = 0; kd < 2; ++kd) {
        int row = c * 16 + fr;
        f16x8 kf = *(const f16x8*)((const char*)lK + row * 128 + ((kd * 64 + fg * 16) ^ ((row & 7) << 4)));
        z = __builtin_amdgcn_mfma_f32_16x16x32_f16(qf[kd], kf, z, 0, 0, 0);
      }
      s[c] = z;
    }
    // online softmax (rows = fg*4+r, cols = c*16+fr)
    float rmax[4];
#pragma unroll
    for (int r = 0; r < 4; r++) {
      float a0 = fmaxf(s[0][r], s[1][r]), a1 = fmaxf(s[2][r], s[3][r]);
      rmax[r] = fmaxf(a0, a1) * SC;
    }
#pragma unroll
    for (int off = 1; off < 16; off <<= 1)
#pragma unroll
      for (int r = 0; r < 4; r++) rmax[r] = fmaxf(rmax[r], __shfl_xor(rmax[r], off));
    float fs[4], rsum[4];
#pragma unroll
    for (int r = 0; r < 4; r++) {
      float mn = fmaxf(m_r[r], rmax[r]);
      fs[r] = __builtin_amdgcn_exp2f(m_r[r] - mn);
      m_r[r] = mn;
      rsum[r] = 0.f;
    }
    float pv[4][4];
#pragma unroll
    for (int c = 0; c < 4; c++)
#pragma unroll
      for (int r = 0; r < 4; r++) {
        float p = __builtin_amdgcn_exp2f(s[c][r] * SC - m_r[r]);
        pv[c][r] = p;
        rsum[r] += p;
      }
#pragma unroll
    for (int off = 1; off < 16; off <<= 1)
#pragma unroll
      for (int r = 0; r < 4; r++) rsum[r] += __shfl_xor(rsum[r], off);
#pragma unroll
    for (int r = 0; r < 4; r++) l_r[r] = l_r[r] * fs[r] + rsum[r];
#pragma unroll
    for (int c = 0; c < 4; c++)
#pragma unroll
      for (int r = 0; r < 4; r++) acc[c][r] *= fs[r];
    // P -> LDS (re-layout to A-fragment distribution)
#pragma unroll
    for (int c = 0; c < 4; c++)
#pragma unroll
      for (int r = 0; r < 4; r++)
        Pw[(fg * 4 + r) * 72 + c * 16 + fr] = f2h(pv[c][r]);
    // PV: acc[c] += P[16 x 64sk] @ V[64sk x 16d]
    f16x8 pf[2];
#pragma unroll
    for (int ks = 0; ks < 2; ks++)
      pf[ks] = *(const f16x8*)((const char*)Pw + fr * 144 + ks * 64 + fg * 16);
#pragma unroll
    for (int c = 0; c < 4; c++)
#pragma unroll
      for (int ks = 0; ks < 2; ks++) {
        int row = c * 16 + fr;
        f16x8 vf = *(const f16x8*)((const char*)lV + row * 128 + ((ks * 64 + fg * 16) ^ ((row & 7) << 4)));
        acc[c] = __builtin_amdgcn_mfma_f32_16x16x32_f16(pf[ks], vf, acc[c], 0, 0, 0);
      }
    __syncthreads();
  }
#pragma unroll
  for (int r = 0; r < 4; r++) {
    float inv = 1.0f / l_r[r];
    int row = qb + wave * 16 + fg * 4 + r;
    u16* dst = AO + (size_t)(b * SS + row) * NE + h * HD;
#pragma unroll
    for (int c = 0; c < 4; c++) dst[c * 16 + fr] = f2h(acc[c][r] * inv);
  }
}

extern "C" void kernel_launch(void* const* d_in, const int* in_sizes, int n_in,
                              void* d_out, int out_size, void* d_ws, size_t ws_size,
                              hipStream_t stream) {
  const float* x  = (const float*)d_in[0];
  const float* Wq = (const float*)d_in[1]; const float* bq = (const float*)d_in[2];
  const float* Wk = (const float*)d_in[3]; const float* bk = (const float*)d_in[4];
  const float* Wv = (const float*)d_in[5]; const float* bv = (const float*)d_in[6];
  const float* Wo = (const float*)d_in[7]; const float* bo = (const float*)d_in[8];

  // workspace layout (fp16 elems). Total = 8M + 4M + 3*8M = 36M elems = 72 MB.
  u16* xb  = (u16*)d_ws;                       // [8192][1024]
  u16* WT  = xb  + (size_t)MR * NE;            // 4 x [1024][1024]
  u16* Qb  = WT  + (size_t)4 * NE * NE;        // [8192][1024]
  u16* Kb  = Qb  + (size_t)MR * NE;            // [8192][1024]
  u16* VTb = Kb  + (size_t)MR * NE;            // [B][H][D][S]
  u16* AOb = xb;                               // reuse xb after projections

  k_cvt_x<<<dim3(MR * NE / (256 * 8)), 256, 0, stream>>>(x, xb);
  k_wt<<<dim3(16, 16, 4), 256, 0, stream>>>(Wq, Wk, Wv, Wo, WT);

  dim3 gg(MR / 128, NE / 128);
  k_gemm<0><<<gg, 256, 0, stream>>>(xb, WT + 0 * (size_t)NE * NE, bq, Qb);
  k_gemm<0><<<gg, 256, 0, stream>>>(xb, WT + 1 * (size_t)NE * NE, bk, Kb);
  k_gemm<1><<<gg, 256, 0, stream>>>(xb, WT + 2 * (size_t)NE * NE, bv, VTb);

  k_attn<<<dim3(SS / 64, NH, SB), 256, 0, stream>>>(Qb, Kb, VTb, AOb);

  k_gemm<2><<<gg, 256, 0, stream>>>(AOb, WT + 3 * (size_t)NE * NE, bo, (float*)d_out);
}

// Round 4
// 240.518 us; speedup vs baseline: 1.2985x; 1.2985x over previous
//
#include <hip/hip_runtime.h>
#include <hip/hip_bf16.h>

#define DEVI static __device__ __forceinline__

typedef __attribute__((ext_vector_type(8))) _Float16 f16x8;
typedef __attribute__((ext_vector_type(4))) float f32x4;
typedef __attribute__((ext_vector_type(8))) unsigned short u16x8;
typedef unsigned short u16;

constexpr int NE = 1024;   // n_embd
constexpr int NH = 16;     // heads
constexpr int HD = 64;     // head dim
constexpr int SB = 4;      // batch
constexpr int SS = 2048;   // seq
constexpr int MR = SB * SS; // 8192 rows

DEVI u16 f2h(float f) {
  union { _Float16 h; u16 u; } x;
  x.h = (_Float16)f;
  return x.u;
}

DEVI void gload_lds16(const void* g, void* l) {
  __builtin_amdgcn_global_load_lds(
      (const __attribute__((address_space(1))) unsigned int*)g,
      (__attribute__((address_space(3))) unsigned int*)l, 16, 0, 0);
}

// ---------------- x fp32 -> fp16 ----------------
__global__ void k_cvt_x(const float* __restrict__ x, u16* __restrict__ xb) {
  size_t i = (size_t)blockIdx.x * 256 + threadIdx.x;
  const f32x4* s4 = (const f32x4*)x;
  f32x4 a = s4[2 * i], c = s4[2 * i + 1];
  u16x8 o;
  o[0] = f2h(a[0]); o[1] = f2h(a[1]); o[2] = f2h(a[2]); o[3] = f2h(a[3]);
  o[4] = f2h(c[0]); o[5] = f2h(c[1]); o[6] = f2h(c[2]); o[7] = f2h(c[3]);
  ((u16x8*)xb)[i] = o;
}

// ---------------- W [K][N] fp32 -> W^T [N][K] fp16 (4 weights) ----------------
__global__ void k_wt(const float* __restrict__ W0, const float* __restrict__ W1,
                     const float* __restrict__ W2, const float* __restrict__ W3,
                     u16* __restrict__ WT) {
  __shared__ float tile[64][65];
  const float* W = (blockIdx.z == 0) ? W0 : (blockIdx.z == 1) ? W1 : (blockIdx.z == 2) ? W2 : W3;
  u16* T = WT + (size_t)blockIdx.z * NE * NE;
  int tid = threadIdx.x, c = tid & 63, rr = tid >> 6;
  int ti = blockIdx.y * 64, tj = blockIdx.x * 64;
#pragma unroll
  for (int p = 0; p < 16; p++) {
    int r = p * 4 + rr;
    tile[r][c] = W[(size_t)(ti + r) * NE + tj + c];
  }
  __syncthreads();
#pragma unroll
  for (int p = 0; p < 16; p++) {
    int r = p * 4 + rr;
    T[(size_t)(tj + r) * NE + ti + c] = f2h(tile[c][r]);
  }
}

// ---------------- GEMM: C[M][1024] = A[M][1024] @ (BT[1024][1024])^T + bias ----------------
template <int MODE>
__global__ __launch_bounds__(256) void k_gemm(const u16* __restrict__ A,
                                              const u16* __restrict__ BT,
                                              const float* __restrict__ bias,
                                              void* __restrict__ outp) {
  __shared__ __align__(16) u16 lA[128 * 64];
  __shared__ __align__(16) u16 lB[128 * 64];
  const int tid = threadIdx.x;
  const int wave = tid >> 6, lane = tid & 63;
  const int wr = wave >> 1, wc = wave & 1;
  const int fr = lane & 15, fg = lane >> 4;
  const int srow = lane >> 3;
  const int scol = ((lane & 7) ^ srow) * 8;
  const int mb = blockIdx.x, nb = blockIdx.y;
  f32x4 acc[4][4] = {};
  for (int kt = 0; kt < NE / 64; ++kt) {
#pragma unroll
    for (int p = 0; p < 4; p++) {
      int rb = wave * 32 + p * 8;
      gload_lds16(A + (size_t)(mb * 128 + rb + srow) * NE + kt * 64 + scol, lA + rb * 64);
      gload_lds16(BT + (size_t)(nb * 128 + rb + srow) * NE + kt * 64 + scol, lB + rb * 64);
    }
    __syncthreads();
#pragma unroll
    for (int kd = 0; kd < 2; ++kd) {
      f16x8 af[4], bg[4];
#pragma unroll
      for (int mi = 0; mi < 4; mi++) {
        int row = wr * 64 + mi * 16 + fr;
        af[mi] = *(const f16x8*)((const char*)lA + row * 128 + ((kd * 64 + fg * 16) ^ ((row & 7) << 4)));
      }
#pragma unroll
      for (int nj = 0; nj < 4; nj++) {
        int row = wc * 64 + nj * 16 + fr;
        bg[nj] = *(const f16x8*)((const char*)lB + row * 128 + ((kd * 64 + fg * 16) ^ ((row & 7) << 4)));
      }
#pragma unroll
      for (int mi = 0; mi < 4; mi++)
#pragma unroll
        for (int nj = 0; nj < 4; nj++)
          acc[mi][nj] = __builtin_amdgcn_mfma_f32_16x16x32_f16(af[mi], bg[nj], acc[mi][nj], 0, 0, 0);
    }
    __syncthreads();
  }
  float bv[4];
#pragma unroll
  for (int nj = 0; nj < 4; nj++) bv[nj] = bias[nb * 128 + wc * 64 + nj * 16 + fr];
#pragma unroll
  for (int mi = 0; mi < 4; mi++)
#pragma unroll
    for (int nj = 0; nj < 4; nj++)
#pragma unroll
      for (int r = 0; r < 4; r++) {
        int row = mb * 128 + wr * 64 + mi * 16 + fg * 4 + r;
        int col = nb * 128 + wc * 64 + nj * 16 + fr;
        float v = acc[mi][nj][r] + bv[nj];
        if constexpr (MODE == 2) {
          ((float*)outp)[(size_t)row * NE + col] = v;
        } else if constexpr (MODE == 0) {
          ((u16*)outp)[(size_t)row * NE + col] = f2h(v);
        } else {
          int b = row >> 11, s = row & (SS - 1);
          int h = col >> 6, d = col & 63;
          ((u16*)outp)[(((size_t)(b * NH + h) * HD + d) << 11) | (size_t)s] = f2h(v);
        }
      }
}

// ---------------- flash attention (swapped-operand, dbuf, defer-max) ----------------
// grid (S/128, H, B), 256 threads. Q,K: [B][S][H*D] fp16. VT: [B][H][D][S] fp16. AO: [B][S][H*D] fp16.
__global__ __launch_bounds__(256) void k_attn(const u16* __restrict__ Q, const u16* __restrict__ K,
                                              const u16* __restrict__ VT, u16* __restrict__ AO) {
  __shared__ __align__(16) u16 lK[2][64 * 64];
  __shared__ __align__(16) u16 lV[2][64 * 64];   // V^T tiles: [d][sk]
  __shared__ __align__(16) u16 lP[4][32 * 72];   // per-wave P [q][k], stride 144 B
  const int tid = threadIdx.x, wave = tid >> 6, lane = tid & 63;
  const int fr = lane & 15, fg = lane >> 4;
  const int srow = lane >> 3;
  const int scol = ((lane & 7) ^ srow) * 8;
  const int qb = blockIdx.x * 128, h = blockIdx.y, b = blockIdx.z;
  const u16* Kg = K + (size_t)(b * SS) * NE + h * HD;
  const u16* Vg = VT + (size_t)(b * NH + h) * HD * SS;
  // Q fragments: lane holds Q[q = fr (per group)][d = kd*32 + fg*8 ..]
  f16x8 qf[2][2];
#pragma unroll
  for (int g = 0; g < 2; g++) {
    const u16* Qp = Q + (size_t)(b * SS + qb + wave * 32 + g * 16 + fr) * NE + h * HD;
    qf[g][0] = *(const f16x8*)(Qp + fg * 8);
    qf[g][1] = *(const f16x8*)(Qp + 32 + fg * 8);
  }
  f32x4 acc[2][4] = {};          // O^T: acc[g][c2], row d = c2*16+fg*4+r, col q = fr
  float m_s[2] = {-1e30f, -1e30f}, l_s[2] = {0.f, 0.f};
  const float SC = 8.0f * 1.44269504088896340736f;   // sqrt(64)*log2(e)
  u16* Pw = &lP[wave][0];

  auto STAGE = [&](int kt2, int bufi) {
    u16* lk = &lK[bufi][0];
    u16* lv = &lV[bufi][0];
#pragma unroll
    for (int p = 0; p < 2; p++) {
      int rb = wave * 16 + p * 8;
      gload_lds16(Kg + (size_t)(kt2 * 64 + rb + srow) * NE + scol, lk + rb * 64);
      gload_lds16(Vg + (size_t)(rb + srow) * SS + kt2 * 64 + scol, lv + rb * 64);
    }
  };

  STAGE(0, 0);
  for (int kt = 0; kt < SS / 64; ++kt) {
    const int cur = kt & 1;
    __syncthreads();                       // drains prev stage (vmcnt) + protects buf reuse
    if (kt + 1 < SS / 64) STAGE(kt + 1, cur ^ 1);
    const u16* lk = &lK[cur][0];
    const u16* lv = &lV[cur][0];
#pragma unroll
    for (int g = 0; g < 2; g++) {
      // S^T = K Q^T : row = k_local = c*16+fg*4+r, col = q = fr
      f32x4 st[4];
#pragma unroll
      for (int c = 0; c < 4; c++) {
        f32x4 z = {};
#pragma unroll
        for (int kd = 0; kd < 2; ++kd) {
          int row = c * 16 + fr;
          f16x8 kf = *(const f16x8*)((const char*)lk + row * 128 + ((kd * 64 + fg * 16) ^ ((row & 7) << 4)));
          z = __builtin_amdgcn_mfma_f32_16x16x32_f16(kf, qf[g][kd], z, 0, 0, 0);
        }
        st[c] = z;
      }
      // row max for q = fr (14 in-register fmax + 2 shuffles), t-domain = raw*SC
      float rmax = fmaxf(fmaxf(fmaxf(st[0][0], st[0][1]), fmaxf(st[0][2], st[0][3])),
                         fmaxf(fmaxf(st[1][0], st[1][1]), fmaxf(st[1][2], st[1][3])));
      float rm2  = fmaxf(fmaxf(fmaxf(st[2][0], st[2][1]), fmaxf(st[2][2], st[2][3])),
                         fmaxf(fmaxf(st[3][0], st[3][1]), fmaxf(st[3][2], st[3][3])));
      rmax = fmaxf(rmax, rm2) * SC;
      rmax = fmaxf(rmax, __shfl_xor(rmax, 16));
      rmax = fmaxf(rmax, __shfl_xor(rmax, 32));
      float mo = m_s[g];
      float mu = mo;
      if (!__all(rmax <= mo + 8.f)) {      // defer-max: skip rescale on small growth
        float nm = fmaxf(mo, rmax);
        float fs = __builtin_amdgcn_exp2f(mo - nm);
        m_s[g] = nm; mu = nm;
        l_s[g] *= fs;
#pragma unroll
        for (int c2 = 0; c2 < 4; c2++)
#pragma unroll
          for (int r = 0; r < 4; r++) acc[g][c2][r] *= fs;
      }
      // P = exp2(t - mu), pack fp16, per-wave LDS round trip (no barrier: wave-private)
      float rs = 0.f;
#pragma unroll
      for (int c = 0; c < 4; c++) {
        union { _Float16 h[4]; unsigned long long u; } pk;
#pragma unroll
        for (int r = 0; r < 4; r++) {
          float p = __builtin_amdgcn_exp2f(st[c][r] * SC - mu);
          rs += p;
          pk.h[r] = (_Float16)p;
        }
        *(unsigned long long*)((char*)Pw + (g * 16 + fr) * 144 + c * 32 + fg * 8) = pk.u;
      }
      rs += __shfl_xor(rs, 16);
      rs += __shfl_xor(rs, 32);
      l_s[g] += rs;
      // PV (swapped): O^T += V^T_frag * P_frag
      f16x8 pf[2];
#pragma unroll
      for (int ks = 0; ks < 2; ks++)
        pf[ks] = *(const f16x8*)((const char*)Pw + (g * 16 + fr) * 144 + ks * 64 + fg * 16);
#pragma unroll
      for (int c2 = 0; c2 < 4; c2++)
#pragma unroll
        for (int ks = 0; ks < 2; ks++) {
          int row = c2 * 16 + fr;
          f16x8 vf = *(const f16x8*)((const char*)lv + row * 128 + ((ks * 64 + fg * 16) ^ ((row & 7) << 4)));
          acc[g][c2] = __builtin_amdgcn_mfma_f32_16x16x32_f16(vf, pf[ks], acc[g][c2], 0, 0, 0);
        }
    }
  }
  // epilogue: O[q][d] = acc^T / l
#pragma unroll
  for (int g = 0; g < 2; g++) {
    float inv = 1.0f / l_s[g];
    u16* dst = AO + (size_t)(b * SS + qb + wave * 32 + g * 16 + fr) * NE + h * HD;
#pragma unroll
    for (int c2 = 0; c2 < 4; c2++) {
      union { _Float16 h[4]; unsigned long long u; } o;
#pragma unroll
      for (int r = 0; r < 4; r++) o.h[r] = (_Float16)(acc[g][c2][r] * inv);
      *(unsigned long long*)(dst + c2 * 16 + fg * 4) = o.u;
    }
  }
}

extern "C" void kernel_launch(void* const* d_in, const int* in_sizes, int n_in,
                              void* d_out, int out_size, void* d_ws, size_t ws_size,
                              hipStream_t stream) {
  const float* x  = (const float*)d_in[0];
  const float* Wq = (const float*)d_in[1]; const float* bq = (const float*)d_in[2];
  const float* Wk = (const float*)d_in[3]; const float* bk = (const float*)d_in[4];
  const float* Wv = (const float*)d_in[5]; const float* bv = (const float*)d_in[6];
  const float* Wo = (const float*)d_in[7]; const float* bo = (const float*)d_in[8];

  u16* xb  = (u16*)d_ws;                       // [8192][1024]
  u16* WT  = xb  + (size_t)MR * NE;            // 4 x [1024][1024]
  u16* Qb  = WT  + (size_t)4 * NE * NE;        // [8192][1024]
  u16* Kb  = Qb  + (size_t)MR * NE;            // [8192][1024]
  u16* VTb = Kb  + (size_t)MR * NE;            // [B][H][D][S]
  u16* AOb = xb;                               // reuse xb after projections

  k_cvt_x<<<dim3(MR * NE / (256 * 8)), 256, 0, stream>>>(x, xb);
  k_wt<<<dim3(16, 16, 4), 256, 0, stream>>>(Wq, Wk, Wv, Wo, WT);

  dim3 gg(MR / 128, NE / 128);
  k_gemm<0><<<gg, 256, 0, stream>>>(xb, WT + 0 * (size_t)NE * NE, bq, Qb);
  k_gemm<0><<<gg, 256, 0, stream>>>(xb, WT + 1 * (size_t)NE * NE, bk, Kb);
  k_gemm<1><<<gg, 256, 0, stream>>>(xb, WT + 2 * (size_t)NE * NE, bv, VTb);

  k_attn<<<dim3(SS / 128, NH, SB), 256, 0, stream>>>(Qb, Kb, VTb, AOb);

  k_gemm<2><<<gg, 256, 0, stream>>>(AOb, WT + 3 * (size_t)NE * NE, bo, (float*)d_out);
}

// Round 9
// 225.341 us; speedup vs baseline: 1.3859x; 1.0673x over previous
//
#include <hip/hip_runtime.h>
#include <hip/hip_bf16.h>

#define DEVI static __device__ __forceinline__

typedef __attribute__((ext_vector_type(8))) _Float16 f16x8;
typedef __attribute__((ext_vector_type(2))) __fp16 fp16v2;   // cvt_pkrtz return type
typedef __attribute__((ext_vector_type(4))) float f32x4;
typedef __attribute__((ext_vector_type(16))) float f32x16;
typedef __attribute__((ext_vector_type(8))) unsigned short u16x8;
typedef __attribute__((ext_vector_type(4))) unsigned int u32x4;
typedef unsigned short u16;

constexpr int NE = 1024;   // n_embd
constexpr int NH = 16;     // heads
constexpr int HD = 64;     // head dim
constexpr int SB = 4;      // batch
constexpr int SS = 2048;   // seq
constexpr int MR = SB * SS; // 8192 rows

DEVI u16 f2h(float f) {
  union { _Float16 h; u16 u; } x;
  x.h = (_Float16)f;
  return x.u;
}

DEVI unsigned pk2(float lo, float hi) {
  union { fp16v2 h2; unsigned u; } cv;
  cv.h2 = __builtin_amdgcn_cvt_pkrtz(lo, hi);
  return cv.u;
}

DEVI void gload_lds16(const void* g, void* l) {
  __builtin_amdgcn_global_load_lds(
      (const __attribute__((address_space(1))) unsigned int*)g,
      (__attribute__((address_space(3))) unsigned int*)l, 16, 0, 0);
}

// ---------------- x fp32 -> fp16 ----------------
__global__ void k_cvt_x(const float* __restrict__ x, u16* __restrict__ xb) {
  size_t i = (size_t)blockIdx.x * 256 + threadIdx.x;
  const f32x4* s4 = (const f32x4*)x;
  f32x4 a = s4[2 * i], c = s4[2 * i + 1];
  u16x8 o;
  o[0] = f2h(a[0]); o[1] = f2h(a[1]); o[2] = f2h(a[2]); o[3] = f2h(a[3]);
  o[4] = f2h(c[0]); o[5] = f2h(c[1]); o[6] = f2h(c[2]); o[7] = f2h(c[3]);
  ((u16x8*)xb)[i] = o;
}

// ---------------- W [K][N] fp32 -> W^T [N][K] fp16 (4 weights) ----------------
__global__ void k_wt(const float* __restrict__ W0, const float* __restrict__ W1,
                     const float* __restrict__ W2, const float* __restrict__ W3,
                     u16* __restrict__ WT) {
  __shared__ float tile[64][65];
  const float* W = (blockIdx.z == 0) ? W0 : (blockIdx.z == 1) ? W1 : (blockIdx.z == 2) ? W2 : W3;
  u16* T = WT + (size_t)blockIdx.z * NE * NE;
  int tid = threadIdx.x, c = tid & 63, rr = tid >> 6;
  int ti = blockIdx.y * 64, tj = blockIdx.x * 64;
#pragma unroll
  for (int p = 0; p < 16; p++) {
    int r = p * 4 + rr;
    tile[r][c] = W[(size_t)(ti + r) * NE + tj + c];
  }
  __syncthreads();
#pragma unroll
  for (int p = 0; p < 16; p++) {
    int r = p * 4 + rr;
    T[(size_t)(tj + r) * NE + ti + c] = f2h(tile[c][r]);
  }
}

// ---------------- GEMM: C[M][1024] = A[M][1024] @ (BT[1024][1024])^T + bias ----------------
template <int MODE>
__global__ __launch_bounds__(256) void k_gemm(const u16* __restrict__ A,
                                              const u16* __restrict__ BT,
                                              const float* __restrict__ bias,
                                              void* __restrict__ outp) {
  __shared__ __align__(16) u16 lA[128 * 64];
  __shared__ __align__(16) u16 lB[128 * 64];
  const int tid = threadIdx.x;
  const int wave = tid >> 6, lane = tid & 63;
  const int wr = wave >> 1, wc = wave & 1;
  const int fr = lane & 15, fg = lane >> 4;
  const int srow = lane >> 3;
  const int scol = ((lane & 7) ^ srow) * 8;
  const int mb = blockIdx.x, nb = blockIdx.y;
  f32x4 acc[4][4] = {};
  for (int kt = 0; kt < NE / 64; ++kt) {
#pragma unroll
    for (int p = 0; p < 4; p++) {
      int rb = wave * 32 + p * 8;
      gload_lds16(A + (size_t)(mb * 128 + rb + srow) * NE + kt * 64 + scol, lA + rb * 64);
      gload_lds16(BT + (size_t)(nb * 128 + rb + srow) * NE + kt * 64 + scol, lB + rb * 64);
    }
    __syncthreads();
#pragma unroll
    for (int kd = 0; kd < 2; ++kd) {
      f16x8 af[4], bg[4];
#pragma unroll
      for (int mi = 0; mi < 4; mi++) {
        int row = wr * 64 + mi * 16 + fr;
        af[mi] = *(const f16x8*)((const char*)lA + row * 128 + ((kd * 64 + fg * 16) ^ ((row & 7) << 4)));
      }
#pragma unroll
      for (int nj = 0; nj < 4; nj++) {
        int row = wc * 64 + nj * 16 + fr;
        bg[nj] = *(const f16x8*)((const char*)lB + row * 128 + ((kd * 64 + fg * 16) ^ ((row & 7) << 4)));
      }
#pragma unroll
      for (int mi = 0; mi < 4; mi++)
#pragma unroll
        for (int nj = 0; nj < 4; nj++)
          acc[mi][nj] = __builtin_amdgcn_mfma_f32_16x16x32_f16(af[mi], bg[nj], acc[mi][nj], 0, 0, 0);
    }
    __syncthreads();
  }
  float bv[4];
#pragma unroll
  for (int nj = 0; nj < 4; nj++) bv[nj] = bias[nb * 128 + wc * 64 + nj * 16 + fr];
#pragma unroll
  for (int mi = 0; mi < 4; mi++)
#pragma unroll
    for (int nj = 0; nj < 4; nj++)
#pragma unroll
      for (int r = 0; r < 4; r++) {
        int row = mb * 128 + wr * 64 + mi * 16 + fg * 4 + r;
        int col = nb * 128 + wc * 64 + nj * 16 + fr;
        float v = acc[mi][nj][r] + bv[nj];
        if constexpr (MODE == 2) {
          ((float*)outp)[(size_t)row * NE + col] = v;
        } else if constexpr (MODE == 0) {
          ((u16*)outp)[(size_t)row * NE + col] = f2h(v);
        } else {
          int b = row >> 11, s = row & (SS - 1);
          int h = col >> 6, d = col & 63;
          ((u16*)outp)[(((size_t)(b * NH + h) * HD + d) << 11) | (size_t)s] = f2h(v);
        }
      }
}

// ---------------- flash attention: 32x32 MFMA, in-register P exchange ----------------
// grid (S/128, H, B), 256 threads (4 waves x 32 q-rows).
// Q,K: [B][S][H*D] fp16. VT: [B][H][D][S] fp16. AO: [B][S][H*D] fp16.
__global__ __launch_bounds__(256) void k_attn(const u16* __restrict__ Q, const u16* __restrict__ K,
                                              const u16* __restrict__ VT, u16* __restrict__ AO) {
  __shared__ __align__(16) u16 smem[4 * 4096];   // [K0|K1|V0|V1], each 64x64 fp16 (32 KB)
  const int tid = threadIdx.x, wave = tid >> 6, lane = tid & 63;
  const int q32 = lane & 31, hh = lane >> 5;     // q column; half-wave index
  const int srow = lane >> 3;
  const int scol = ((lane & 7) ^ srow) * 8;
  const int qb = blockIdx.x * 128, h = blockIdx.y, b = blockIdx.z;
  const u16* Kg = K + (size_t)(b * SS) * NE + h * HD;
  const u16* Vg = VT + (size_t)(b * NH + h) * HD * SS;
  const u16* Qp = Q + (size_t)(b * SS + qb + wave * 32 + q32) * NE + h * HD;
  // Q B-fragments: qf[m] = Q[q32][m*16 + hh*8 .. +7]
  f16x8 qf[4];
#pragma unroll
  for (int m = 0; m < 4; m++) qf[m] = *(const f16x8*)(Qp + m * 16 + hh * 8);
  f32x16 oacc[2] = {};               // O^T: row d = d2*32 + (r&3)+8*(r>>2)+4*hh, col q = q32
  float m_s = -1e30f, l_s = 0.f;
  const float SC = 8.0f * 1.44269504088896340736f;   // sqrt(64)*log2(e)

  auto STAGE = [&](int kt2, int bufi) {
    u16* lk = smem + bufi * 4096;
    u16* lv = smem + 8192 + bufi * 4096;
#pragma unroll
    for (int p = 0; p < 2; p++) {
      int rb = wave * 16 + p * 8;
      gload_lds16(Kg + (size_t)(kt2 * 64 + rb + srow) * NE + scol, lk + rb * 64);
      gload_lds16(Vg + (size_t)(rb + srow) * SS + kt2 * 64 + scol, lv + rb * 64);
    }
  };

  STAGE(0, 0);
  for (int kt = 0; kt < SS / 64; ++kt) {
    const int cur = kt & 1;
    __syncthreads();                       // prev stage drained; buffers safe
    if (kt + 1 < SS / 64) STAGE(kt + 1, cur ^ 1);
    const u16* lk = smem + cur * 4096;
    const u16* lv = smem + 8192 + cur * 4096;
    // S^T[k][q] = K·Q^T : two 32x32 tiles over k
    f32x16 sacc[2];
#pragma unroll
    for (int kt32 = 0; kt32 < 2; kt32++) {
      f32x16 z = {};
      int row = kt32 * 32 + q32;
#pragma unroll
      for (int m = 0; m < 4; m++) {
        f16x8 kf = *(const f16x8*)((const char*)lk + row * 128 + ((m * 32 + hh * 16) ^ ((row & 7) << 4)));
        z = __builtin_amdgcn_mfma_f32_32x32x16_f16(kf, qf[m], z, 0, 0, 0);
      }
      sacc[kt32] = z;
    }
    // row max over the 64 k (lane holds 32; partner l^32 holds the rest)
    float mx = sacc[0][0];
#pragma unroll
    for (int r = 1; r < 16; r++) mx = fmaxf(mx, sacc[0][r]);
#pragma unroll
    for (int r = 0; r < 16; r++) mx = fmaxf(mx, sacc[1][r]);
    mx *= SC;
    mx = fmaxf(mx, __shfl_xor(mx, 32));
    float mo = m_s, mu = mo;
    if (!__all(mx <= mo + 8.f)) {          // defer-max
      float nm = fmaxf(mo, mx);
      float fs = __builtin_amdgcn_exp2f(mo - nm);
      m_s = nm; mu = nm; l_s *= fs;
#pragma unroll
      for (int d2 = 0; d2 < 2; d2++)
#pragma unroll
        for (int r = 0; r < 16; r++) oacc[d2][r] *= fs;
    }
    float rs = 0.f;
    float p[2][16];
#pragma unroll
    for (int kt32 = 0; kt32 < 2; kt32++)
#pragma unroll
      for (int r = 0; r < 16; r++) {
        float pv = __builtin_amdgcn_exp2f(sacc[kt32][r] * SC - mu);
        p[kt32][r] = pv;
        rs += pv;
      }
    rs += __shfl_xor(rs, 32);
    l_s += rs;
    // pack P pairs: W[kt32][a][b2] = f16(p[4a+2b2], p[4a+2b2+1]); k0 = kt32*32 + 8a + 4hh + 2b2
    unsigned W[2][4][2];
#pragma unroll
    for (int kt32 = 0; kt32 < 2; kt32++)
#pragma unroll
      for (int a = 0; a < 4; a++)
#pragma unroll
        for (int b2 = 0; b2 < 2; b2++)
          W[kt32][a][b2] = pk2(p[kt32][4 * a + 2 * b2], p[kt32][4 * a + 2 * b2 + 1]);
    // redistribute to PV B-fragments: bw[t][w], k = t*16 + hh*8 + 2w
    unsigned bw[4][4];
#pragma unroll
    for (int kt32 = 0; kt32 < 2; kt32++)
#pragma unroll
      for (int tau = 0; tau < 2; tau++)
#pragma unroll
        for (int b2 = 0; b2 < 2; b2++) {
          unsigned Y = W[kt32][2 * tau][b2];       // a = 2tau   (needed by hh=0)
          unsigned X = W[kt32][2 * tau + 1][b2];   // a = 2tau+1 (needed by hh=1)
          unsigned sx = __shfl_xor(X, 32);
          unsigned sy = __shfl_xor(Y, 32);
          int t = kt32 * 2 + tau;
          bw[t][b2]     = hh ? sx : Y;   // from half 0
          bw[t][b2 + 2] = hh ? X : sy;   // from half 1
        }
    // PV: O^T[d][q] += V^T_frag(A) * P_frag(B)
    f16x8 pf[4];
#pragma unroll
    for (int t = 0; t < 4; t++) {
      union { unsigned w[4]; f16x8 v; } u;
#pragma unroll
      for (int w = 0; w < 4; w++) u.w[w] = bw[t][w];
      pf[t] = u.v;
    }
#pragma unroll
    for (int d2 = 0; d2 < 2; d2++) {
      int row = d2 * 32 + q32;
#pragma unroll
      for (int t = 0; t < 4; t++) {
        f16x8 vf = *(const f16x8*)((const char*)lv + row * 128 + ((t * 32 + hh * 16) ^ ((row & 7) << 4)));
        oacc[d2] = __builtin_amdgcn_mfma_f32_32x32x16_f16(vf, pf[t], oacc[d2], 0, 0, 0);
      }
    }
  }
  // ---- epilogue: transpose O^T -> O via LDS, then coalesced global write ----
  __syncthreads();                         // all waves done with lk/lv
  unsigned* epi = (unsigned*)smem + wave * (32 * 36);   // [32 q][36 u32] per wave
  float inv = 1.0f / l_s;
#pragma unroll
  for (int d2 = 0; d2 < 2; d2++)
#pragma unroll
    for (int a = 0; a < 4; a++)
#pragma unroll
      for (int b2 = 0; b2 < 2; b2++) {
        int r0 = 4 * a + 2 * b2;
        epi[q32 * 36 + d2 * 16 + 4 * a + 2 * hh + b2] =
            pk2(oacc[d2][r0] * inv, oacc[d2][r0 + 1] * inv);
      }
  __syncthreads();
  {
    int q2 = lane >> 1, part = lane & 1;
    const unsigned* src = (const unsigned*)smem + wave * (32 * 36) + q2 * 36 + part * 16;
    u16* dst = AO + (size_t)(b * SS + qb + wave * 32 + q2) * NE + h * HD + part * 32;
#pragma unroll
    for (int u = 0; u < 4; u++)
      *(u32x4*)(dst + u * 8) = *(const u32x4*)(src + u * 4);
  }
}

extern "C" void kernel_launch(void* const* d_in, const int* in_sizes, int n_in,
                              void* d_out, int out_size, void* d_ws, size_t ws_size,
                              hipStream_t stream) {
  const float* x  = (const float*)d_in[0];
  const float* Wq = (const float*)d_in[1]; const float* bq = (const float*)d_in[2];
  const float* Wk = (const float*)d_in[3]; const float* bk = (const float*)d_in[4];
  const float* Wv = (const float*)d_in[5]; const float* bv = (const float*)d_in[6];
  const float* Wo = (const float*)d_in[7]; const float* bo = (const float*)d_in[8];

  u16* xb  = (u16*)d_ws;                       // [8192][1024]
  u16* WT  = xb  + (size_t)MR * NE;            // 4 x [1024][1024]
  u16* Qb  = WT  + (size_t)4 * NE * NE;        // [8192][1024]
  u16* Kb  = Qb  + (size_t)MR * NE;            // [8192][1024]
  u16* VTb = Kb  + (size_t)MR * NE;            // [B][H][D][S]
  u16* AOb = xb;                               // reuse xb after projections

  k_cvt_x<<<dim3(MR * NE / (256 * 8)), 256, 0, stream>>>(x, xb);
  k_wt<<<dim3(16, 16, 4), 256, 0, stream>>>(Wq, Wk, Wv, Wo, WT);

  dim3 gg(MR / 128, NE / 128);
  k_gemm<0><<<gg, 256, 0, stream>>>(xb, WT + 0 * (size_t)NE * NE, bq, Qb);
  k_gemm<0><<<gg, 256, 0, stream>>>(xb, WT + 1 * (size_t)NE * NE, bk, Kb);
  k_gemm<1><<<gg, 256, 0, stream>>>(xb, WT + 2 * (size_t)NE * NE, bv, VTb);

  k_attn<<<dim3(SS / 128, NH, SB), 256, 0, stream>>>(Qb, Kb, VTb, AOb);

  k_gemm<2><<<gg, 256, 0, stream>>>(AOb, WT + 3 * (size_t)NE * NE, bo, (float*)d_out);
}

// Round 10
// 224.141 us; speedup vs baseline: 1.3934x; 1.0054x over previous
//
#include <hip/hip_runtime.h>
#include <hip/hip_bf16.h>

#define DEVI static __device__ __forceinline__

typedef __attribute__((ext_vector_type(8))) _Float16 f16x8;
typedef __attribute__((ext_vector_type(2))) __fp16 fp16v2;   // cvt_pkrtz return type
typedef __attribute__((ext_vector_type(4))) float f32x4;
typedef __attribute__((ext_vector_type(16))) float f32x16;
typedef __attribute__((ext_vector_type(8))) unsigned short u16x8;
typedef __attribute__((ext_vector_type(4))) unsigned int u32x4;
typedef __attribute__((ext_vector_type(2))) unsigned int u32x2;
typedef unsigned short u16;

constexpr int NE = 1024;   // n_embd
constexpr int NH = 16;     // heads
constexpr int HD = 64;     // head dim
constexpr int SB = 4;      // batch
constexpr int SS = 2048;   // seq
constexpr int MR = SB * SS; // 8192 rows

DEVI u16 f2h(float f) {
  union { _Float16 h; u16 u; } x;
  x.h = (_Float16)f;
  return x.u;
}

DEVI unsigned pk2(float lo, float hi) {
  union { fp16v2 h2; unsigned u; } cv;
  cv.h2 = __builtin_amdgcn_cvt_pkrtz(lo, hi);
  return cv.u;
}

DEVI void gload_lds16(const void* g, void* l) {
  __builtin_amdgcn_global_load_lds(
      (const __attribute__((address_space(1))) unsigned int*)g,
      (__attribute__((address_space(3))) unsigned int*)l, 16, 0, 0);
}

// ---------------- x fp32 -> fp16 ----------------
__global__ void k_cvt_x(const float* __restrict__ x, u16* __restrict__ xb) {
  size_t i = (size_t)blockIdx.x * 256 + threadIdx.x;
  const f32x4* s4 = (const f32x4*)x;
  f32x4 a = s4[2 * i], c = s4[2 * i + 1];
  u16x8 o;
  o[0] = f2h(a[0]); o[1] = f2h(a[1]); o[2] = f2h(a[2]); o[3] = f2h(a[3]);
  o[4] = f2h(c[0]); o[5] = f2h(c[1]); o[6] = f2h(c[2]); o[7] = f2h(c[3]);
  ((u16x8*)xb)[i] = o;
}

// ---------------- W [K][N] fp32 -> W^T [N][K] fp16 (4 weights) ----------------
__global__ void k_wt(const float* __restrict__ W0, const float* __restrict__ W1,
                     const float* __restrict__ W2, const float* __restrict__ W3,
                     u16* __restrict__ WT) {
  __shared__ float tile[64][65];
  const float* W = (blockIdx.z == 0) ? W0 : (blockIdx.z == 1) ? W1 : (blockIdx.z == 2) ? W2 : W3;
  u16* T = WT + (size_t)blockIdx.z * NE * NE;
  int tid = threadIdx.x, c = tid & 63, rr = tid >> 6;
  int ti = blockIdx.y * 64, tj = blockIdx.x * 64;
#pragma unroll
  for (int p = 0; p < 16; p++) {
    int r = p * 4 + rr;
    tile[r][c] = W[(size_t)(ti + r) * NE + tj + c];
  }
  __syncthreads();
#pragma unroll
  for (int p = 0; p < 16; p++) {
    int r = p * 4 + rr;
    T[(size_t)(tj + r) * NE + ti + c] = f2h(tile[c][r]);
  }
}

// ---------------- GEMM: C[M][1024] = A[M][1024] @ (BT[1024][1024])^T + bias ----------------
template <int MODE>
__global__ __launch_bounds__(256) void k_gemm(const u16* __restrict__ A,
                                              const u16* __restrict__ BT,
                                              const float* __restrict__ bias,
                                              void* __restrict__ outp) {
  __shared__ __align__(16) u16 lA[128 * 64];
  __shared__ __align__(16) u16 lB[128 * 64];
  const int tid = threadIdx.x;
  const int wave = tid >> 6, lane = tid & 63;
  const int wr = wave >> 1, wc = wave & 1;
  const int fr = lane & 15, fg = lane >> 4;
  const int srow = lane >> 3;
  const int scol = ((lane & 7) ^ srow) * 8;
  const int mb = blockIdx.x, nb = blockIdx.y;
  f32x4 acc[4][4] = {};
  for (int kt = 0; kt < NE / 64; ++kt) {
#pragma unroll
    for (int p = 0; p < 4; p++) {
      int rb = wave * 32 + p * 8;
      gload_lds16(A + (size_t)(mb * 128 + rb + srow) * NE + kt * 64 + scol, lA + rb * 64);
      gload_lds16(BT + (size_t)(nb * 128 + rb + srow) * NE + kt * 64 + scol, lB + rb * 64);
    }
    __syncthreads();
#pragma unroll
    for (int kd = 0; kd < 2; ++kd) {
      f16x8 af[4], bg[4];
#pragma unroll
      for (int mi = 0; mi < 4; mi++) {
        int row = wr * 64 + mi * 16 + fr;
        af[mi] = *(const f16x8*)((const char*)lA + row * 128 + ((kd * 64 + fg * 16) ^ ((row & 7) << 4)));
      }
#pragma unroll
      for (int nj = 0; nj < 4; nj++) {
        int row = wc * 64 + nj * 16 + fr;
        bg[nj] = *(const f16x8*)((const char*)lB + row * 128 + ((kd * 64 + fg * 16) ^ ((row & 7) << 4)));
      }
#pragma unroll
      for (int mi = 0; mi < 4; mi++)
#pragma unroll
        for (int nj = 0; nj < 4; nj++)
          acc[mi][nj] = __builtin_amdgcn_mfma_f32_16x16x32_f16(af[mi], bg[nj], acc[mi][nj], 0, 0, 0);
    }
    __syncthreads();
  }
  float bv[4];
#pragma unroll
  for (int nj = 0; nj < 4; nj++) bv[nj] = bias[nb * 128 + wc * 64 + nj * 16 + fr];
#pragma unroll
  for (int mi = 0; mi < 4; mi++)
#pragma unroll
    for (int nj = 0; nj < 4; nj++)
#pragma unroll
      for (int r = 0; r < 4; r++) {
        int row = mb * 128 + wr * 64 + mi * 16 + fg * 4 + r;
        int col = nb * 128 + wc * 64 + nj * 16 + fr;
        float v = acc[mi][nj][r] + bv[nj];
        if constexpr (MODE == 2) {
          ((float*)outp)[(size_t)row * NE + col] = v;
        } else if constexpr (MODE == 0) {
          ((u16*)outp)[(size_t)row * NE + col] = f2h(v);
        } else {
          int b = row >> 11, s = row & (SS - 1);
          int h = col >> 6, d = col & 63;
          ((u16*)outp)[(((size_t)(b * NH + h) * HD + d) << 11) | (size_t)s] = f2h(v);
        }
      }
}

// ---------------- flash attention: 32x32 MFMA, permlane P exchange, setprio ----------------
// grid (S/128, H, B), 256 threads (4 waves x 32 q-rows).
// Q,K: [B][S][H*D] fp16. VT: [B][H][D][S] fp16. AO: [B][S][H*D] fp16.
__global__ __launch_bounds__(256) void k_attn(const u16* __restrict__ Q, const u16* __restrict__ K,
                                              const u16* __restrict__ VT, u16* __restrict__ AO) {
  __shared__ __align__(16) u16 smem[4 * 4096];   // [K0|K1|V0|V1], each 64x64 fp16 (32 KB)
  const int tid = threadIdx.x, wave = tid >> 6, lane = tid & 63;
  const int q32 = lane & 31, hh = lane >> 5;     // q column; half-wave index
  const int srow = lane >> 3;
  const int scol = ((lane & 7) ^ srow) * 8;
  const int qb = blockIdx.x * 128, h = blockIdx.y, b = blockIdx.z;
  const u16* Kg = K + (size_t)(b * SS) * NE + h * HD;
  const u16* Vg = VT + (size_t)(b * NH + h) * HD * SS;
  const u16* Qp = Q + (size_t)(b * SS + qb + wave * 32 + q32) * NE + h * HD;
  // Q B-fragments: qf[m] = Q[q32][m*16 + hh*8 .. +7]
  f16x8 qf[4];
#pragma unroll
  for (int m = 0; m < 4; m++) qf[m] = *(const f16x8*)(Qp + m * 16 + hh * 8);
  f32x16 oacc[2] = {};               // O^T: row d = d2*32 + (r&3)+8*(r>>2)+4*hh, col q = q32
  float m_s = -1e30f, l_s = 0.f;
  const float SC = 8.0f * 1.44269504088896340736f;   // sqrt(64)*log2(e)

  auto STAGE = [&](int kt2, int bufi) {
    u16* lk = smem + bufi * 4096;
    u16* lv = smem + 8192 + bufi * 4096;
#pragma unroll
    for (int p = 0; p < 2; p++) {
      int rb = wave * 16 + p * 8;
      gload_lds16(Kg + (size_t)(kt2 * 64 + rb + srow) * NE + scol, lk + rb * 64);
      gload_lds16(Vg + (size_t)(rb + srow) * SS + kt2 * 64 + scol, lv + rb * 64);
    }
  };

  STAGE(0, 0);
  for (int kt = 0; kt < SS / 64; ++kt) {
    const int cur = kt & 1;
    __syncthreads();                       // prev stage drained; buffers safe
    if (kt + 1 < SS / 64) STAGE(kt + 1, cur ^ 1);
    const u16* lk = smem + cur * 4096;
    const u16* lv = smem + 8192 + cur * 4096;
    // S^T[k][q] = K·Q^T : two 32x32 tiles over k
    f32x16 sacc[2];
#pragma unroll
    for (int kt32 = 0; kt32 < 2; kt32++) {
      f32x16 z = {};
      int row = kt32 * 32 + q32;
      __builtin_amdgcn_s_setprio(1);
#pragma unroll
      for (int m = 0; m < 4; m++) {
        f16x8 kf = *(const f16x8*)((const char*)lk + row * 128 + ((m * 32 + hh * 16) ^ ((row & 7) << 4)));
        z = __builtin_amdgcn_mfma_f32_32x32x16_f16(kf, qf[m], z, 0, 0, 0);
      }
      __builtin_amdgcn_s_setprio(0);
      sacc[kt32] = z;
    }
    // row max over the 64 k: tree (depth 5), then cross-half combine
    float a[16];
#pragma unroll
    for (int r = 0; r < 16; r++) a[r] = fmaxf(sacc[0][r], sacc[1][r]);
#pragma unroll
    for (int s = 8; s > 0; s >>= 1)
#pragma unroll
      for (int r = 0; r < s; r++) a[r] = fmaxf(a[r], a[r + s]);
    float mx = a[0] * SC;
    mx = fmaxf(mx, __shfl_xor(mx, 32));
    float mo = m_s, mu = mo;
    if (!__all(mx <= mo + 8.f)) {          // defer-max
      float nm = fmaxf(mo, mx);
      float fs = __builtin_amdgcn_exp2f(mo - nm);
      m_s = nm; mu = nm; l_s *= fs;
#pragma unroll
      for (int d2 = 0; d2 < 2; d2++)
#pragma unroll
        for (int r = 0; r < 16; r++) oacc[d2][r] *= fs;
    }
    float p[2][16];
#pragma unroll
    for (int kt32 = 0; kt32 < 2; kt32++)
#pragma unroll
      for (int r = 0; r < 16; r++)
        p[kt32][r] = __builtin_amdgcn_exp2f(sacc[kt32][r] * SC - mu);
    // row-sum tree
    float t[16];
#pragma unroll
    for (int r = 0; r < 16; r++) t[r] = p[0][r] + p[1][r];
#pragma unroll
    for (int s = 8; s > 0; s >>= 1)
#pragma unroll
      for (int r = 0; r < s; r++) t[r] += t[r + s];
    float rs = t[0];
    rs += __shfl_xor(rs, 32);
    l_s += rs;
    // pack P pairs: W[kt32][a][b2] = f16(p[4a+2b2], p[4a+2b2+1]); k0 = kt32*32 + 8a + 4hh + 2b2
    unsigned W[2][4][2];
#pragma unroll
    for (int kt32 = 0; kt32 < 2; kt32++)
#pragma unroll
      for (int aa = 0; aa < 4; aa++)
#pragma unroll
        for (int b2 = 0; b2 < 2; b2++)
          W[kt32][aa][b2] = pk2(p[kt32][4 * aa + 2 * b2], p[kt32][4 * aa + 2 * b2 + 1]);
    // redistribute via permlane32_swap: pair (a, a+1) -> words w=b2 and w=b2+2 of chunk t
    // swap(A,B): A' = {A_lo, B_lo(moved up)}, B' = {A_hi(moved down), B_hi}
    unsigned bw[4][4];
#pragma unroll
    for (int kt32 = 0; kt32 < 2; kt32++)
#pragma unroll
      for (int tau = 0; tau < 2; tau++)
#pragma unroll
        for (int b2 = 0; b2 < 2; b2++) {
          u32x2 r2 = __builtin_amdgcn_permlane32_swap(W[kt32][2 * tau][b2], W[kt32][2 * tau + 1][b2],
                                                      false, false);
          int tt = kt32 * 2 + tau;
          bw[tt][b2]     = r2[0];
          bw[tt][b2 + 2] = r2[1];
        }
    // PV: O^T[d][q] += V^T_frag(A) * P_frag(B)
    f16x8 pf[4];
#pragma unroll
    for (int tt = 0; tt < 4; tt++) {
      union { unsigned w[4]; f16x8 v; } u;
#pragma unroll
      for (int w = 0; w < 4; w++) u.w[w] = bw[tt][w];
      pf[tt] = u.v;
    }
#pragma unroll
    for (int d2 = 0; d2 < 2; d2++) {
      int row = d2 * 32 + q32;
      __builtin_amdgcn_s_setprio(1);
#pragma unroll
      for (int tt = 0; tt < 4; tt++) {
        f16x8 vf = *(const f16x8*)((const char*)lv + row * 128 + ((tt * 32 + hh * 16) ^ ((row & 7) << 4)));
        oacc[d2] = __builtin_amdgcn_mfma_f32_32x32x16_f16(vf, pf[tt], oacc[d2], 0, 0, 0);
      }
      __builtin_amdgcn_s_setprio(0);
    }
  }
  // ---- epilogue: transpose O^T -> O via LDS, then coalesced global write ----
  __syncthreads();                         // all waves done with lk/lv
  unsigned* epi = (unsigned*)smem + wave * (32 * 36);   // [32 q][36 u32] per wave
  float inv = 1.0f / l_s;
#pragma unroll
  for (int d2 = 0; d2 < 2; d2++)
#pragma unroll
    for (int aa = 0; aa < 4; aa++)
#pragma unroll
      for (int b2 = 0; b2 < 2; b2++) {
        int r0 = 4 * aa + 2 * b2;
        epi[q32 * 36 + d2 * 16 + 4 * aa + 2 * hh + b2] =
            pk2(oacc[d2][r0] * inv, oacc[d2][r0 + 1] * inv);
      }
  __syncthreads();
  {
    int q2 = lane >> 1, part = lane & 1;
    const unsigned* src = (const unsigned*)smem + wave * (32 * 36) + q2 * 36 + part * 16;
    u16* dst = AO + (size_t)(b * SS + qb + wave * 32 + q2) * NE + h * HD + part * 32;
#pragma unroll
    for (int u = 0; u < 4; u++)
      *(u32x4*)(dst + u * 8) = *(const u32x4*)(src + u * 4);
  }
}

extern "C" void kernel_launch(void* const* d_in, const int* in_sizes, int n_in,
                              void* d_out, int out_size, void* d_ws, size_t ws_size,
                              hipStream_t stream) {
  const float* x  = (const float*)d_in[0];
  const float* Wq = (const float*)d_in[1]; const float* bq = (const float*)d_in[2];
  const float* Wk = (const float*)d_in[3]; const float* bk = (const float*)d_in[4];
  const float* Wv = (const float*)d_in[5]; const float* bv = (const float*)d_in[6];
  const float* Wo = (const float*)d_in[7]; const float* bo = (const float*)d_in[8];

  u16* xb  = (u16*)d_ws;                       // [8192][1024]
  u16* WT  = xb  + (size_t)MR * NE;            // 4 x [1024][1024]
  u16* Qb  = WT  + (size_t)4 * NE * NE;        // [8192][1024]
  u16* Kb  = Qb  + (size_t)MR * NE;            // [8192][1024]
  u16* VTb = Kb  + (size_t)MR * NE;            // [B][H][D][S]
  u16* AOb = xb;                               // reuse xb after projections

  k_cvt_x<<<dim3(MR * NE / (256 * 8)), 256, 0, stream>>>(x, xb);
  k_wt<<<dim3(16, 16, 4), 256, 0, stream>>>(Wq, Wk, Wv, Wo, WT);

  dim3 gg(MR / 128, NE / 128);
  k_gemm<0><<<gg, 256, 0, stream>>>(xb, WT + 0 * (size_t)NE * NE, bq, Qb);
  k_gemm<0><<<gg, 256, 0, stream>>>(xb, WT + 1 * (size_t)NE * NE, bk, Kb);
  k_gemm<1><<<gg, 256, 0, stream>>>(xb, WT + 2 * (size_t)NE * NE, bv, VTb);

  k_attn<<<dim3(SS / 128, NH, SB), 256, 0, stream>>>(Qb, Kb, VTb, AOb);

  k_gemm<2><<<gg, 256, 0, stream>>>(AOb, WT + 3 * (size_t)NE * NE, bo, (float*)d_out);
}

// Round 11
// 222.089 us; speedup vs baseline: 1.4062x; 1.0092x over previous
//
#include <hip/hip_runtime.h>
#include <hip/hip_bf16.h>

#define DEVI static __device__ __forceinline__

typedef __attribute__((ext_vector_type(8))) _Float16 f16x8;
typedef __attribute__((ext_vector_type(2))) __fp16 fp16v2;   // cvt_pkrtz return type
typedef __attribute__((ext_vector_type(4))) float f32x4;
typedef __attribute__((ext_vector_type(16))) float f32x16;
typedef __attribute__((ext_vector_type(8))) unsigned short u16x8;
typedef __attribute__((ext_vector_type(4))) unsigned int u32x4;
typedef __attribute__((ext_vector_type(2))) unsigned int u32x2;
typedef unsigned short u16;

constexpr int NE = 1024;   // n_embd
constexpr int NH = 16;     // heads
constexpr int HD = 64;     // head dim
constexpr int SB = 4;      // batch
constexpr int SS = 2048;   // seq
constexpr int MR = SB * SS; // 8192 rows

DEVI u16 f2h(float f) {
  union { _Float16 h; u16 u; } x;
  x.h = (_Float16)f;
  return x.u;
}

DEVI unsigned pk2(float lo, float hi) {
  union { fp16v2 h2; unsigned u; } cv;
  cv.h2 = __builtin_amdgcn_cvt_pkrtz(lo, hi);
  return cv.u;
}

DEVI void gload_lds16(const void* g, void* l) {
  __builtin_amdgcn_global_load_lds(
      (const __attribute__((address_space(1))) unsigned int*)g,
      (__attribute__((address_space(3))) unsigned int*)l, 16, 0, 0);
}

// ---------------- x fp32 -> fp16 ----------------
__global__ void k_cvt_x(const float* __restrict__ x, u16* __restrict__ xb) {
  size_t i = (size_t)blockIdx.x * 256 + threadIdx.x;
  const f32x4* s4 = (const f32x4*)x;
  f32x4 a = s4[2 * i], c = s4[2 * i + 1];
  u16x8 o;
  o[0] = f2h(a[0]); o[1] = f2h(a[1]); o[2] = f2h(a[2]); o[3] = f2h(a[3]);
  o[4] = f2h(c[0]); o[5] = f2h(c[1]); o[6] = f2h(c[2]); o[7] = f2h(c[3]);
  ((u16x8*)xb)[i] = o;
}

// ---------------- W [K][N] fp32 -> W^T [N][K] fp16 (4 weights) ----------------
__global__ void k_wt(const float* __restrict__ W0, const float* __restrict__ W1,
                     const float* __restrict__ W2, const float* __restrict__ W3,
                     u16* __restrict__ WT) {
  __shared__ float tile[64][65];
  const float* W = (blockIdx.z == 0) ? W0 : (blockIdx.z == 1) ? W1 : (blockIdx.z == 2) ? W2 : W3;
  u16* T = WT + (size_t)blockIdx.z * NE * NE;
  int tid = threadIdx.x, c = tid & 63, rr = tid >> 6;
  int ti = blockIdx.y * 64, tj = blockIdx.x * 64;
#pragma unroll
  for (int p = 0; p < 16; p++) {
    int r = p * 4 + rr;
    tile[r][c] = W[(size_t)(ti + r) * NE + tj + c];
  }
  __syncthreads();
#pragma unroll
  for (int p = 0; p < 16; p++) {
    int r = p * 4 + rr;
    T[(size_t)(tj + r) * NE + ti + c] = f2h(tile[c][r]);
  }
}

// ---------------- GEMM: C[M][1024] = A[M][1024] @ (BT[1024][1024])^T + bias ----------------
template <int MODE>
__global__ __launch_bounds__(256) void k_gemm(const u16* __restrict__ A,
                                              const u16* __restrict__ BT,
                                              const float* __restrict__ bias,
                                              void* __restrict__ outp) {
  __shared__ __align__(16) u16 lA[128 * 64];
  __shared__ __align__(16) u16 lB[128 * 64];
  const int tid = threadIdx.x;
  const int wave = tid >> 6, lane = tid & 63;
  const int wr = wave >> 1, wc = wave & 1;
  const int fr = lane & 15, fg = lane >> 4;
  const int srow = lane >> 3;
  const int scol = ((lane & 7) ^ srow) * 8;
  const int mb = blockIdx.x, nb = blockIdx.y;
  f32x4 acc[4][4] = {};
  for (int kt = 0; kt < NE / 64; ++kt) {
#pragma unroll
    for (int p = 0; p < 4; p++) {
      int rb = wave * 32 + p * 8;
      gload_lds16(A + (size_t)(mb * 128 + rb + srow) * NE + kt * 64 + scol, lA + rb * 64);
      gload_lds16(BT + (size_t)(nb * 128 + rb + srow) * NE + kt * 64 + scol, lB + rb * 64);
    }
    __syncthreads();
#pragma unroll
    for (int kd = 0; kd < 2; ++kd) {
      f16x8 af[4], bg[4];
#pragma unroll
      for (int mi = 0; mi < 4; mi++) {
        int row = wr * 64 + mi * 16 + fr;
        af[mi] = *(const f16x8*)((const char*)lA + row * 128 + ((kd * 64 + fg * 16) ^ ((row & 7) << 4)));
      }
#pragma unroll
      for (int nj = 0; nj < 4; nj++) {
        int row = wc * 64 + nj * 16 + fr;
        bg[nj] = *(const f16x8*)((const char*)lB + row * 128 + ((kd * 64 + fg * 16) ^ ((row & 7) << 4)));
      }
#pragma unroll
      for (int mi = 0; mi < 4; mi++)
#pragma unroll
        for (int nj = 0; nj < 4; nj++)
          acc[mi][nj] = __builtin_amdgcn_mfma_f32_16x16x32_f16(af[mi], bg[nj], acc[mi][nj], 0, 0, 0);
    }
    __syncthreads();
  }
  float bv[4];
#pragma unroll
  for (int nj = 0; nj < 4; nj++) bv[nj] = bias[nb * 128 + wc * 64 + nj * 16 + fr];
#pragma unroll
  for (int mi = 0; mi < 4; mi++)
#pragma unroll
    for (int nj = 0; nj < 4; nj++)
#pragma unroll
      for (int r = 0; r < 4; r++) {
        int row = mb * 128 + wr * 64 + mi * 16 + fg * 4 + r;
        int col = nb * 128 + wc * 64 + nj * 16 + fr;
        float v = acc[mi][nj][r] + bv[nj];
        if constexpr (MODE == 2) {
          ((float*)outp)[(size_t)row * NE + col] = v;
        } else if constexpr (MODE == 0) {
          ((u16*)outp)[(size_t)row * NE + col] = f2h(v);
        } else {
          int b = row >> 11, s = row & (SS - 1);
          int h = col >> 6, d = col & 63;
          ((u16*)outp)[(((size_t)(b * NH + h) * HD + d) << 11) | (size_t)s] = f2h(v);
        }
      }
}

// ---------------- flash attention: 32x32 MFMA, T15 2-stream pipeline, 3-buf LDS ----------------
// grid 1024 (XCD-swizzled 1D), 256 threads (4 waves x 32 q-rows).
// Q,K: [B][S][H*D] fp16. VT: [B][H][D][S] fp16. AO: [B][S][H*D] fp16.
__global__ __launch_bounds__(256) void k_attn(const u16* __restrict__ Q, const u16* __restrict__ K,
                                              const u16* __restrict__ VT, u16* __restrict__ AO) {
  __shared__ __align__(16) u16 smem[6 * 4096];   // K0..K2 | V0..V2, each 64x64 fp16 (48 KB)
  const int tid = threadIdx.x, wave = tid >> 6, lane = tid & 63;
  const int q32 = lane & 31, hh = lane >> 5;     // q column; half-wave index
  const int srow = lane >> 3;
  const int scol = ((lane & 7) ^ srow) * 8;
  // XCD-aware decode: all 16 q-blocks of one (b,h) land on one XCD (bid%8 assumption)
  const int bid = blockIdx.x;
  const int xcd = bid & 7, idx = bid >> 3;
  const int g = xcd * 8 + (idx >> 4);            // (b,h) group in [0,64)
  const int qb = (idx & 15) * 128;
  const int b = g >> 4, h = g & 15;
  const u16* Kg = K + (size_t)(b * SS) * NE + h * HD;
  const u16* Vg = VT + (size_t)(b * NH + h) * HD * SS;
  const u16* Qp = Q + (size_t)(b * SS + qb + wave * 32 + q32) * NE + h * HD;
  // Q B-fragments: qf[m] = Q[q32][m*16 + hh*8 .. +7]
  f16x8 qf[4];
#pragma unroll
  for (int m = 0; m < 4; m++) qf[m] = *(const f16x8*)(Qp + m * 16 + hh * 8);
  f32x16 oacc[2] = {};               // O^T: row d = d2*32 + (r&3)+8*(r>>2)+4*hh, col q = q32
  float m_s = -1e30f, l_s = 0.f;
  const float SC = 8.0f * 1.44269504088896340736f;   // sqrt(64)*log2(e)

  auto STAGE = [&](int kt2, int bufi) {
    u16* lk = smem + bufi * 4096;
    u16* lv = smem + 12288 + bufi * 4096;
#pragma unroll
    for (int p = 0; p < 2; p++) {
      int rb = wave * 16 + p * 8;
      gload_lds16(Kg + (size_t)(kt2 * 64 + rb + srow) * NE + scol, lk + rb * 64);
      gload_lds16(Vg + (size_t)(rb + srow) * SS + kt2 * 64 + scol, lv + rb * 64);
    }
  };

  // S^T[k][q] = K·Q^T for one 64-k tile -> s[2] (two 32x32 accs)
  auto QK = [&](int bufi, f32x16* s) {
    const u16* lk = smem + bufi * 4096;
#pragma unroll
    for (int kt32 = 0; kt32 < 2; kt32++) {
      f32x16 z = {};
      int row = kt32 * 32 + q32;
      __builtin_amdgcn_s_setprio(1);
#pragma unroll
      for (int m = 0; m < 4; m++) {
        f16x8 kf = *(const f16x8*)((const char*)lk + row * 128 + ((m * 32 + hh * 16) ^ ((row & 7) << 4)));
        z = __builtin_amdgcn_mfma_f32_32x32x16_f16(kf, qf[m], z, 0, 0, 0);
      }
      __builtin_amdgcn_s_setprio(0);
      s[kt32] = z;
    }
  };

  // softmax(s) + PV with V tile in buf bufiV; updates m_s, l_s, oacc
  auto SMPV = [&](int bufiV, f32x16* s) {
    const u16* lv = smem + 12288 + bufiV * 4096;
    float a[16];
#pragma unroll
    for (int r = 0; r < 16; r++) a[r] = fmaxf(s[0][r], s[1][r]);
#pragma unroll
    for (int st = 8; st > 0; st >>= 1)
#pragma unroll
      for (int r = 0; r < st; r++) a[r] = fmaxf(a[r], a[r + st]);
    float mx = a[0] * SC;
    mx = fmaxf(mx, __shfl_xor(mx, 32));
    float mo = m_s, mu = mo;
    if (!__all(mx <= mo + 8.f)) {          // defer-max
      float nm = fmaxf(mo, mx);
      float fs = __builtin_amdgcn_exp2f(mo - nm);
      m_s = nm; mu = nm; l_s *= fs;
#pragma unroll
      for (int d2 = 0; d2 < 2; d2++)
#pragma unroll
        for (int r = 0; r < 16; r++) oacc[d2][r] *= fs;
    }
    float p[2][16];
#pragma unroll
    for (int kt32 = 0; kt32 < 2; kt32++)
#pragma unroll
      for (int r = 0; r < 16; r++)
        p[kt32][r] = __builtin_amdgcn_exp2f(s[kt32][r] * SC - mu);
    float t[16];
#pragma unroll
    for (int r = 0; r < 16; r++) t[r] = p[0][r] + p[1][r];
#pragma unroll
    for (int st = 8; st > 0; st >>= 1)
#pragma unroll
      for (int r = 0; r < st; r++) t[r] += t[r + st];
    float rs = t[0];
    rs += __shfl_xor(rs, 32);
    l_s += rs;
    // pack + permlane32_swap redistribute -> PV B-fragments
    unsigned bw[4][4];
#pragma unroll
    for (int kt32 = 0; kt32 < 2; kt32++)
#pragma unroll
      for (int tau = 0; tau < 2; tau++)
#pragma unroll
        for (int b2 = 0; b2 < 2; b2++) {
          unsigned Y = pk2(p[kt32][4 * (2 * tau) + 2 * b2],     p[kt32][4 * (2 * tau) + 2 * b2 + 1]);
          unsigned X = pk2(p[kt32][4 * (2 * tau + 1) + 2 * b2], p[kt32][4 * (2 * tau + 1) + 2 * b2 + 1]);
          u32x2 r2 = __builtin_amdgcn_permlane32_swap(Y, X, false, false);
          int tt = kt32 * 2 + tau;
          bw[tt][b2]     = r2[0];
          bw[tt][b2 + 2] = r2[1];
        }
    f16x8 pf[4];
#pragma unroll
    for (int tt = 0; tt < 4; tt++) {
      union { unsigned w[4]; f16x8 v; } u;
#pragma unroll
      for (int w = 0; w < 4; w++) u.w[w] = bw[tt][w];
      pf[tt] = u.v;
    }
#pragma unroll
    for (int d2 = 0; d2 < 2; d2++) {
      int row = d2 * 32 + q32;
      __builtin_amdgcn_s_setprio(1);
#pragma unroll
      for (int tt = 0; tt < 4; tt++) {
        f16x8 vf = *(const f16x8*)((const char*)lv + row * 128 + ((tt * 32 + hh * 16) ^ ((row & 7) << 4)));
        oacc[d2] = __builtin_amdgcn_mfma_f32_32x32x16_f16(vf, pf[tt], oacc[d2], 0, 0, 0);
      }
      __builtin_amdgcn_s_setprio(0);
    }
  };

  // ---- T15 pipeline: QK(t) overlaps softmax/PV of tile t-1; 3-buffer rotation ----
  f32x16 sA[2], sB[2];
  STAGE(0, 0);
  STAGE(1, 1);
  __syncthreads();
  QK(0, sA);
  for (int t = 1; t < 31; t += 2) {
    __syncthreads();                 // K[t] ready (staged last iter); frees buf (t+1)%3
    STAGE(t + 1, (t + 1) % 3);
    QK(t % 3, sB);                   // MFMA on tile t — overlaps softmax below
    SMPV((t - 1) % 3, sA);           // softmax+PV of tile t-1
    __syncthreads();
    STAGE(t + 2, (t + 2) % 3);
    QK((t + 1) % 3, sA);
    SMPV(t % 3, sB);
  }
  __syncthreads();                   // drains STAGE(31)
  QK(31 % 3, sB);
  SMPV(30 % 3, sA);
  SMPV(31 % 3, sB);

  // ---- epilogue: transpose O^T -> O via LDS, then coalesced global write ----
  __syncthreads();                   // all waves done with K/V buffers
  unsigned* epi = (unsigned*)smem + wave * (32 * 36);   // [32 q][36 u32] per wave
  float inv = 1.0f / l_s;
#pragma unroll
  for (int d2 = 0; d2 < 2; d2++)
#pragma unroll
    for (int aa = 0; aa < 4; aa++)
#pragma unroll
      for (int b2 = 0; b2 < 2; b2++) {
        int r0 = 4 * aa + 2 * b2;
        epi[q32 * 36 + d2 * 16 + 4 * aa + 2 * hh + b2] =
            pk2(oacc[d2][r0] * inv, oacc[d2][r0 + 1] * inv);
      }
  __syncthreads();
  {
    int q2 = lane >> 1, part = lane & 1;
    const unsigned* src = (const unsigned*)smem + wave * (32 * 36) + q2 * 36 + part * 16;
    u16* dst = AO + (size_t)(b * SS + qb + wave * 32 + q2) * NE + h * HD + part * 32;
#pragma unroll
    for (int u = 0; u < 4; u++)
      *(u32x4*)(dst + u * 8) = *(const u32x4*)(src + u * 4);
  }
}

extern "C" void kernel_launch(void* const* d_in, const int* in_sizes, int n_in,
                              void* d_out, int out_size, void* d_ws, size_t ws_size,
                              hipStream_t stream) {
  const float* x  = (const float*)d_in[0];
  const float* Wq = (const float*)d_in[1]; const float* bq = (const float*)d_in[2];
  const float* Wk = (const float*)d_in[3]; const float* bk = (const float*)d_in[4];
  const float* Wv = (const float*)d_in[5]; const float* bv = (const float*)d_in[6];
  const float* Wo = (const float*)d_in[7]; const float* bo = (const float*)d_in[8];

  u16* xb  = (u16*)d_ws;                       // [8192][1024]
  u16* WT  = xb  + (size_t)MR * NE;            // 4 x [1024][1024]
  u16* Qb  = WT  + (size_t)4 * NE * NE;        // [8192][1024]
  u16* Kb  = Qb  + (size_t)MR * NE;            // [8192][1024]
  u16* VTb = Kb  + (size_t)MR * NE;            // [B][H][D][S]
  u16* AOb = xb;                               // reuse xb after projections

  k_cvt_x<<<dim3(MR * NE / (256 * 8)), 256, 0, stream>>>(x, xb);
  k_wt<<<dim3(16, 16, 4), 256, 0, stream>>>(Wq, Wk, Wv, Wo, WT);

  dim3 gg(MR / 128, NE / 128);
  k_gemm<0><<<gg, 256, 0, stream>>>(xb, WT + 0 * (size_t)NE * NE, bq, Qb);
  k_gemm<0><<<gg, 256, 0, stream>>>(xb, WT + 1 * (size_t)NE * NE, bk, Kb);
  k_gemm<1><<<gg, 256, 0, stream>>>(xb, WT + 2 * (size_t)NE * NE, bv, VTb);

  k_attn<<<dim3(1024), 256, 0, stream>>>(Qb, Kb, VTb, AOb);

  k_gemm<2><<<gg, 256, 0, stream>>>(AOb, WT + 3 * (size_t)NE * NE, bo, (float*)d_out);
}